// Round 7
// baseline (115.988 us; speedup 1.0000x reference)
//
#include <hip/hip_runtime.h>

// StericClashConstraint: N=16384 pts [N,3] fp32.
// out[0..3N-1] = pos passthrough; out[3N] = mean(max(1-dist,0), diag=0) * 0.02
//
// Round 7: R6 kernel was only ~50% VALU duty at 4 blocks/CU (occupancy-starved
// for latency hiding of the scalar j-stream loads + branch fences). Change:
// grid 2048 = exactly 8 blocks/CU, __launch_bounds__(256,8) -> 32 waves/CU.
// Work per CU identical; stall fraction should drop ~50% -> ~20%.
// Minor: jt4 padded with QB sentinels (drops min() clamps in prefetch),
// fma chain ordered so one SGPR-mov per q suffices (1-SGPR-per-VALU rule).

constexpr int N     = 16384;
constexpr int BLOCK = 256;            // 4 waves
constexpr int IPT   = 8;              // i's per thread
constexpr int IC    = BLOCK * IPT;    // 2048 i's per chunk
constexpr int NXC   = N / IC;         // 8 i-chunks
constexpr int NB    = 2048;           // exactly 8 blocks/CU
constexpr int TCOLS = IC * (NXC * (NXC + 1) / 2);  // 73728 j-columns total
constexpr int CPB   = TCOLS / NB;     // 36 columns per block (exact, mult of QB)
constexpr int QB    = 4;              // j's prefetched per batch

__device__ __forceinline__ constexpr int cum(int x) {
    // columns before chunk x: sum_{x'<x} (NXC-x')*IC
    return IC * (x * NXC - x * (x - 1) / 2);
}

template <bool MASKED>
__device__ __forceinline__ float cols(const float4* __restrict__ jt4,
                                      int j0, int len, int ibt,
                                      const float (&xi2)[IPT], const float (&yi2)[IPT],
                                      const float (&zi2)[IPT], const float (&thr)[IPT],
                                      const float (&sqi)[IPT]) {
    float s = 0.0f;
    if (len <= 0) return s;
    float4 cur[QB];
    #pragma unroll
    for (int u = 0; u < QB; ++u) cur[u] = jt4[j0 + u];          // pad: safe to N+QB-1
    for (int qb = 0; qb < len; qb += QB) {
        float4 nxt[QB];
        #pragma unroll
        for (int u = 0; u < QB; ++u) nxt[u] = jt4[j0 + qb + QB + u];
        #pragma unroll
        for (int u = 0; u < QB; ++u) {
            const float4 pj = cur[u];
            const int jq = j0 + qb + u;
            // base = pj.w + pj.x * xi2 ; chain keeps <=1 SGPR per v_fma after
            // the compiler moves one of {pj.x, pj.w} to a VGPR once per q.
            float tt[IPT];
            unsigned long long m = 0;
            #pragma unroll
            for (int k = 0; k < IPT; ++k) {
                float d = fmaf(xi2[k], pj.x, pj.w);
                d = fmaf(yi2[k], pj.y, d);
                tt[k] = fmaf(zi2[k], pj.z, d);
                bool v = tt[k] < thr[k];
                if (MASKED) v = v && (jq > ibt + k * BLOCK);
                m |= __ballot(v);
            }
            if (m) {                      // one branch per 512 pairs, ~32% taken
                #pragma unroll
                for (int k = 0; k < IPT; ++k) {
                    bool v = tt[k] < thr[k];
                    if (MASKED) v = v && (jq > ibt + k * BLOCK);
                    if (v) {
                        const float d2 = fmaxf(tt[k] + sqi[k], 0.0f);
                        s += 1.0f - __builtin_amdgcn_sqrtf(d2);
                    }
                }
            }
        }
        #pragma unroll
        for (int u = 0; u < QB; ++u) cur[u] = nxt[u];
    }
    return s;
}

__global__ void prep_kernel(const float* __restrict__ pos, float* __restrict__ out,
                            float4* __restrict__ jt4) {
    const int t = blockIdx.x * blockDim.x + threadIdx.x;   // 0..16383
    if (t < (N * 3) / 4) {
        reinterpret_cast<float4*>(out)[t] = reinterpret_cast<const float4*>(pos)[t];
    }
    const float x = pos[3 * t], y = pos[3 * t + 1], z = pos[3 * t + 2];
    jt4[t] = make_float4(x, y, z, fmaf(x, x, fmaf(y, y, z * z)));
    if (t < QB) {     // sentinel pad: far away, never violates (and never used)
        jt4[N + t] = make_float4(1.0e9f, 1.0e9f, 1.0e9f, 3.0e18f);
    }
}

__global__ void __launch_bounds__(BLOCK, 8)
pair_kernel(const float4* __restrict__ jt4, float* __restrict__ out,
            float* __restrict__ acc, unsigned int* __restrict__ cnt) {
    __shared__ float wsum[BLOCK / 64];
    const int b = blockIdx.x;
    const int t = threadIdx.x;

    float s = 0.0f;
    int c = b * CPB;
    const int c1 = c + CPB;

    while (c < c1) {                       // <=2 segments per block
        int x = 0;
        #pragma unroll
        for (int xx = 1; xx < NXC; ++xx)
            if (cum(xx) <= c) x = xx;
        const int segEnd = min(c1, cum(x + 1));
        const int jbase  = x * IC + (c - cum(x));
        const int len    = segEnd - c;     // multiple of 4 by construction
        const int ibt    = x * IC + t;

        float xi2[IPT], yi2[IPT], zi2[IPT], thr[IPT], sqi[IPT];
        #pragma unroll
        for (int k = 0; k < IPT; ++k) {
            const float4 w = jt4[ibt + k * BLOCK];
            xi2[k] = -2.0f * w.x;
            yi2[k] = -2.0f * w.y;
            zi2[k] = -2.0f * w.z;
            sqi[k] = w.w;
            thr[k] = 1.0f - w.w;
        }

        const int maskLen = min(len, max(0, (x + 1) * IC - jbase));
        s += cols<true >(jt4, jbase, maskLen, ibt, xi2, yi2, zi2, thr, sqi);
        s += cols<false>(jt4, jbase + maskLen, len - maskLen, ibt, xi2, yi2, zi2, thr, sqi);
        c = segEnd;
    }

    // reduce: wave shuffle -> LDS -> one atomic per block
    for (int off = 32; off > 0; off >>= 1) s += __shfl_down(s, off);
    if ((t & 63) == 0) wsum[t >> 6] = s;
    __syncthreads();
    if (t == 0) {
        float bs = 0.0f;
        #pragma unroll
        for (int w = 0; w < BLOCK / 64; ++w) bs += wsum[w];
        atomicAdd(acc, bs);
        __threadfence();
        const unsigned int done = atomicAdd(cnt, 1u);
        if (done == (unsigned int)(NB - 1)) {          // last block finalizes
            __threadfence();
            const float total = atomicAdd(acc, 0.0f);  // device-coherent read
            const double mean = 2.0 * (double)total / ((double)N * (double)N);
            out[(size_t)N * 3] = (float)(mean * 0.02);
        }
    }
}

extern "C" void kernel_launch(void* const* d_in, const int* in_sizes, int n_in,
                              void* d_out, int out_size, void* d_ws, size_t ws_size,
                              hipStream_t stream) {
    const float* pos = (const float*)d_in[0];
    float* out = (float*)d_out;
    // ws layout: [acc(4B) cnt(4B) pad..256B) | jt4: (16384+QB) x float4]
    float* acc = (float*)d_ws;
    unsigned int* cnt = (unsigned int*)d_ws + 1;
    float4* jt4 = (float4*)((char*)d_ws + 256);

    hipMemsetAsync(d_ws, 0, 8, stream);   // acc = 0.f, cnt = 0

    prep_kernel<<<N / 256, 256, 0, stream>>>(pos, out, jt4);
    pair_kernel<<<NB, BLOCK, 0, stream>>>(jt4, out, acc, cnt);
}